// Round 2
// baseline (130.202 us; speedup 1.0000x reference)
//
#include <hip/hip_runtime.h>

// Problem constants (from reference setup_inputs)
#define B 4
#define N 8
#define H 384
#define W 384
#define HW (H * W)
#define PIX_PER_THREAD 2   // float2 vectorization

// out[b*N + i][c][h][w] = sum_j softmax_j(-d2[i][j]/alpha) * ab[j][c]
// d2[i][j] = sum_c (lab[j][c] - lab[i][c])^2  (per pixel)
// Note: d2[i][i] == 0 and d2 >= 0  =>  softmax max is exactly 0, no
// max-subtraction needed; exp(-d2/a) in (0,1], sum >= 1.
__global__ __launch_bounds__(256) void wavg_color_temporal_kernel(
    const float* __restrict__ x_lab,   // (B, N, 3, H, W)
    const float* __restrict__ x_ab,    // (B, N, 2, H, W)
    const int*   __restrict__ alpha_p, // scalar (int or float bits)
    float*       __restrict__ out)     // (B*N, 2, H, W)
{
    const int tid = blockIdx.x * blockDim.x + threadIdx.x;
    const int total = B * (HW / PIX_PER_THREAD);
    if (tid >= total) return;

    // alpha: robust to int32 or float32 encoding of the scalar
    int ai = alpha_p[0];
    float alpha;
    if (ai > 0 && ai < (1 << 23)) alpha = (float)ai;      // small int
    else                          alpha = __int_as_float(ai); // float bits
    const float inv_alpha = __builtin_amdgcn_rcpf(alpha);

    const int b = tid / (HW / PIX_PER_THREAD);
    const int p = (tid % (HW / PIX_PER_THREAD)) * PIX_PER_THREAD;

    const float* lab_b = x_lab + (size_t)b * N * 3 * HW + p;
    const float* ab_b  = x_ab  + (size_t)b * N * 2 * HW + p;
    float*       out_b = out   + (size_t)b * N * 2 * HW + p;

    // Stage all inputs for this pixel pair in registers.
    float2 lab[N][3];
    float2 ab[N][2];
#pragma unroll
    for (int j = 0; j < N; ++j) {
#pragma unroll
        for (int c = 0; c < 3; ++c)
            lab[j][c] = *reinterpret_cast<const float2*>(lab_b + (size_t)(j * 3 + c) * HW);
#pragma unroll
        for (int c = 0; c < 2; ++c)
            ab[j][c] = *reinterpret_cast<const float2*>(ab_b + (size_t)(j * 2 + c) * HW);
    }

#pragma unroll
    for (int i = 0; i < N; ++i) {
        float sum_x = 0.f, sum_y = 0.f;
        float a0x = 0.f, a0y = 0.f;   // ab channel 0 accumulators
        float a1x = 0.f, a1y = 0.f;   // ab channel 1 accumulators
#pragma unroll
        for (int j = 0; j < N; ++j) {
            // pixel .x
            float dx0 = lab[j][0].x - lab[i][0].x;
            float dx1 = lab[j][1].x - lab[i][1].x;
            float dx2 = lab[j][2].x - lab[i][2].x;
            float d2x = dx0 * dx0 + dx1 * dx1 + dx2 * dx2;
            float wx  = __expf(-d2x * inv_alpha);
            sum_x += wx;
            a0x += wx * ab[j][0].x;
            a1x += wx * ab[j][1].x;
            // pixel .y
            float dy0 = lab[j][0].y - lab[i][0].y;
            float dy1 = lab[j][1].y - lab[i][1].y;
            float dy2 = lab[j][2].y - lab[i][2].y;
            float d2y = dy0 * dy0 + dy1 * dy1 + dy2 * dy2;
            float wy  = __expf(-d2y * inv_alpha);
            sum_y += wy;
            a0y += wy * ab[j][0].y;
            a1y += wy * ab[j][1].y;
        }
        // sum >= 1 always (j==i contributes exp(0)=1), rcp is safe.
        float rx = __builtin_amdgcn_rcpf(sum_x);
        float ry = __builtin_amdgcn_rcpf(sum_y);
        float2 o0, o1;
        o0.x = a0x * rx; o0.y = a0y * ry;
        o1.x = a1x * rx; o1.y = a1y * ry;
        *reinterpret_cast<float2*>(out_b + (size_t)(i * 2 + 0) * HW) = o0;
        *reinterpret_cast<float2*>(out_b + (size_t)(i * 2 + 1) * HW) = o1;
    }
}

extern "C" void kernel_launch(void* const* d_in, const int* in_sizes, int n_in,
                              void* d_out, int out_size, void* d_ws, size_t ws_size,
                              hipStream_t stream) {
    const float* x_lab = (const float*)d_in[0];
    const float* x_ab  = (const float*)d_in[1];
    const int*   alpha = (const int*)d_in[2];
    float* out = (float*)d_out;

    const int total_threads = B * (HW / PIX_PER_THREAD);   // 4 * 73728 = 294912
    const int block = 256;
    const int grid = (total_threads + block - 1) / block;  // 1152 blocks
    wavg_color_temporal_kernel<<<grid, block, 0, stream>>>(x_lab, x_ab, alpha, out);
}